// Round 1
// baseline (53.625 us; speedup 1.0000x reference)
//
#include <hip/hip_runtime.h>

// Problem constants (fixed by the reference): C_IN=8, C_OUT=32, N_RINGS=2,
// WIDTH=4.0, sigma=4.0, rings={0,4}. n and B derived at runtime.

__device__ __forceinline__ int rev6(int l) {
  return ((l & 1) << 5) | ((l & 2) << 3) | ((l & 4) << 1) |
         ((l & 8) >> 1) | ((l & 16) >> 3) | ((l & 32) >> 5);
}

// In-place recursive-halving reduce-scatter over the 64-lane wave.
// On entry each lane holds v[0..63]; on exit, return value = sum over all
// lanes of original value index rev6(lane).
__device__ __forceinline__ float wave_reduce_scatter64(float* v, int lane) {
  int count = 64;
#pragma unroll
  for (int m = 1; m < 64; m <<= 1) {
    const int half = count >> 1;
    const bool hi = (lane & m) != 0;
#pragma unroll
    for (int k = 0; k < half; ++k) {
      float send = hi ? v[k] : v[half + k];
      float keep = hi ? v[half + k] : v[k];
      float recv = __shfl_xor(send, m, 64);
      v[k] = keep + recv;
    }
    count = half;
  }
  return v[0];
}

// ---------- kernel 1: per-graph count + coord sums -> acc[B][4] ----------
__global__ __launch_bounds__(256) void pool_kernel(
    const float* __restrict__ coords, const int* __restrict__ batch,
    float* __restrict__ acc, int n) {
  int e = blockIdx.x * blockDim.x + threadIdx.x;
  int lane = threadIdx.x & 63;
  int ec = min(e, n - 1);
  bool valid = (e < n);
  int g = batch[ec];
  float s0 = valid ? 1.0f : 0.0f;
  float s1 = valid ? coords[ec * 3 + 0] : 0.0f;
  float s2 = valid ? coords[ec * 3 + 1] : 0.0f;
  float s3 = valid ? coords[ec * 3 + 2] : 0.0f;

  int gfirst = __builtin_amdgcn_readfirstlane(g);
  int glast  = __builtin_amdgcn_readfirstlane(__shfl(g, 63, 64));

  if (gfirst == glast) {
    float t0 = s0, t1 = s1, t2 = s2, t3 = s3;
#pragma unroll
    for (int m = 1; m < 64; m <<= 1) {
      t0 += __shfl_xor(t0, m, 64);
      t1 += __shfl_xor(t1, m, 64);
      t2 += __shfl_xor(t2, m, 64);
      t3 += __shfl_xor(t3, m, 64);
    }
    if (lane < 4) {
      float val = (lane == 0) ? t0 : (lane == 1) ? t1 : (lane == 2) ? t2 : t3;
      atomicAdd(&acc[gfirst * 4 + lane], val);
    }
  } else {
    for (int gc = gfirst; gc <= glast; ++gc) {
      bool in = (g == gc);
      float t0 = in ? s0 : 0.0f, t1 = in ? s1 : 0.0f;
      float t2 = in ? s2 : 0.0f, t3 = in ? s3 : 0.0f;
#pragma unroll
      for (int m = 1; m < 64; m <<= 1) {
        t0 += __shfl_xor(t0, m, 64);
        t1 += __shfl_xor(t1, m, 64);
        t2 += __shfl_xor(t2, m, 64);
        t3 += __shfl_xor(t3, m, 64);
      }
      if (lane < 4) {
        float val = (lane == 0) ? t0 : (lane == 1) ? t1 : (lane == 2) ? t2 : t3;
        atomicAdd(&acc[gc * 4 + lane], val);
      }
    }
  }
}

// ---------- kernel 2: per-edge basis + outer product, segment-sum -> V[B][64]
__global__ __launch_bounds__(256) void edge_kernel(
    const float* __restrict__ x, const float* __restrict__ coords,
    const int* __restrict__ batch, const float* __restrict__ acc,
    float* __restrict__ V, int n) {
  int e = blockIdx.x * blockDim.x + threadIdx.x;
  int lane = threadIdx.x & 63;
  int ec = min(e, n - 1);
  bool valid = (e < n);
  int g = batch[ec];

  float cx = coords[ec * 3 + 0];
  float cy = coords[ec * 3 + 1];
  float cz = coords[ec * 3 + 2];
  float4 a4 = ((const float4*)acc)[g];  // {cnt, sx, sy, sz}
  float inv = 1.0f / fmaxf(a4.x, 1.0f);
  float rx = a4.y * inv - cx;
  float ry = a4.z * inv - cy;
  float rz = a4.w * inv - cz;
  float d2 = rx * rx + ry * ry + rz * rz;
  float d = sqrtf(d2);
  // rings = {0, 4}, sigma = 4
  float r0 = __expf(-0.03125f * d2);          // exp(-0.5*(d/4)^2)
  float tt = (d - 4.0f) * 0.25f;
  float r1 = __expf(-0.5f * tt * tt);
  float idm = 1.0f / fmaxf(d, 1e-6f);
  float ax = rx * idm, ay = ry * idm, az = rz * idm;
  float bas[8] = {r0, r0 * ax, r0 * ay, r0 * az, r1, r1 * ax, r1 * ay, r1 * az};

  float4 xa = ((const float4*)x)[ec * 2];
  float4 xb = ((const float4*)x)[ec * 2 + 1];
  float xv[8] = {xa.x, xa.y, xa.z, xa.w, xb.x, xb.y, xb.z, xb.w};
  if (!valid) {
#pragma unroll
    for (int i = 0; i < 8; ++i) xv[i] = 0.0f;
  }

  int gfirst = __builtin_amdgcn_readfirstlane(g);
  int glast  = __builtin_amdgcn_readfirstlane(__shfl(g, 63, 64));
  int dst = rev6(lane);

  float v[64];
  if (gfirst == glast) {
#pragma unroll
    for (int i = 0; i < 8; ++i)
#pragma unroll
      for (int b = 0; b < 8; ++b) v[i * 8 + b] = xv[i] * bas[b];
    float r = wave_reduce_scatter64(v, lane);
    atomicAdd(&V[(size_t)gfirst * 64 + dst], r);
  } else {
    for (int gc = gfirst; gc <= glast; ++gc) {
      bool in = (g == gc);
#pragma unroll
      for (int i = 0; i < 8; ++i)
#pragma unroll
        for (int b = 0; b < 8; ++b) v[i * 8 + b] = in ? xv[i] * bas[b] : 0.0f;
      float r = wave_reduce_scatter64(v, lane);
      atomicAdd(&V[(size_t)gc * 64 + dst], r);
    }
  }
}

// ---------- kernel 3: out_raw[g,o] = sum_k V[g,k]*W[o,k]; channel stats ----
__global__ __launch_bounds__(256) void gemm_stats_kernel(
    const float* __restrict__ V, const float* __restrict__ W,
    float* __restrict__ out_raw, float* __restrict__ stats, int B) {
  __shared__ float Wl[32][65];   // +1 pad: (65*o+k)%32 = (o+k)%32, conflict-free
  __shared__ float Vl[8][64];
  __shared__ float ssum[32], ssq[32];
  int t = threadIdx.x;
  for (int idx = t; idx < 32 * 64; idx += 256) Wl[idx >> 6][idx & 63] = W[idx];
  int g0 = blockIdx.x * 8;
  for (int idx = t; idx < 8 * 64; idx += 256) Vl[idx >> 6][idx & 63] = V[(size_t)g0 * 64 + idx];
  if (t < 32) { ssum[t] = 0.0f; ssq[t] = 0.0f; }
  __syncthreads();

  int gl = t >> 5;
  int o = t & 31;
  float r = 0.0f;
#pragma unroll
  for (int k = 0; k < 64; ++k) r += Vl[gl][k] * Wl[o][k];
  out_raw[(size_t)(g0 + gl) * 32 + o] = r;
  atomicAdd(&ssum[o], r);
  atomicAdd(&ssq[o], r * r);
  __syncthreads();
  if (t < 32) {
    atomicAdd(&stats[t], ssum[t]);
    atomicAdd(&stats[32 + t], ssq[t]);
  }
}

// ---------- kernel 4: batchnorm + relu(|.|-bias) ----------
__global__ __launch_bounds__(256) void final_kernel(
    const float* __restrict__ out_raw, const float* __restrict__ stats,
    const float* __restrict__ gamma, const float* __restrict__ beta,
    const float* __restrict__ act_bias, float* __restrict__ out, int B) {
  int t = blockIdx.x * blockDim.x + threadIdx.x;
  if (t >= B * 32) return;
  int o = t & 31;
  float invB = 1.0f / (float)B;
  float mu = stats[o] * invB;
  float var = stats[32 + o] * invB - mu * mu;
  float xn = (out_raw[t] - mu) * rsqrtf(var + 1e-5f) * gamma[o] + beta[o];
  float y = fabsf(xn) - act_bias[o];
  out[t] = fmaxf(y, 0.0f);
}

extern "C" void kernel_launch(void* const* d_in, const int* in_sizes, int n_in,
                              void* d_out, int out_size, void* d_ws, size_t ws_size,
                              hipStream_t stream) {
  const float* x      = (const float*)d_in[0];
  const float* coords = (const float*)d_in[1];
  const int*   batch  = (const int*)d_in[2];
  const float* W      = (const float*)d_in[3];
  const float* gamma  = (const float*)d_in[4];
  const float* beta   = (const float*)d_in[5];
  const float* abias  = (const float*)d_in[6];
  float* out = (float*)d_out;

  int n = in_sizes[2];          // N points
  int B = out_size / 32;        // graphs

  // workspace layout (floats): acc[B*4] | V[B*64] | stats[64] | out_raw[B*32]
  float* acc     = (float*)d_ws;
  float* V       = acc + (size_t)B * 4;
  float* stats   = V + (size_t)B * 64;
  float* out_raw = stats + 64;
  size_t zero_bytes = ((size_t)B * 4 + (size_t)B * 64 + 64) * sizeof(float);
  hipMemsetAsync(d_ws, 0, zero_bytes, stream);

  int blk = 256;
  int nblocks = (n + blk - 1) / blk;
  pool_kernel<<<nblocks, blk, 0, stream>>>(coords, batch, acc, n);
  edge_kernel<<<nblocks, blk, 0, stream>>>(x, coords, batch, acc, V, n);
  gemm_stats_kernel<<<B / 8, 256, 0, stream>>>(V, W, out_raw, stats, B);
  final_kernel<<<(B * 32 + 255) / 256, 256, 0, stream>>>(out_raw, stats, gamma, beta, abias, out, B);
}

// Round 2
// 47.579 us; speedup vs baseline: 1.1271x; 1.1271x over previous
//
#include <hip/hip_runtime.h>

// Problem constants (fixed by the reference): C_IN=8, C_OUT=32, N_RINGS=2,
// WIDTH=4.0, sigma=4.0, rings={0,4}. n and B derived at runtime.

__device__ __forceinline__ int rev6(int l) {
  return ((l & 1) << 5) | ((l & 2) << 3) | ((l & 4) << 1) |
         ((l & 8) >> 1) | ((l & 16) >> 3) | ((l & 32) >> 5);
}

// One recursive-halving stage with LITERAL constants so every v[] index is
// compile-time constant (keeps v[] in VGPRs — runtime indexing would demote
// the array to scratch, which was the round-0 disaster).
#define RS_STAGE(M, HALF)                                   \
  {                                                         \
    const bool hi = (lane & (M)) != 0;                      \
    _Pragma("unroll")                                       \
    for (int k = 0; k < (HALF); ++k) {                      \
      float send = hi ? v[k] : v[(HALF) + k];               \
      float keep = hi ? v[(HALF) + k] : v[k];               \
      v[k] = keep + __shfl_xor(send, (M), 64);              \
    }                                                       \
  }

// After all 6 stages, v[0] = sum over lanes of original index rev6(lane).
#define RS_ALL()     \
  RS_STAGE(1, 32)    \
  RS_STAGE(2, 16)    \
  RS_STAGE(4, 8)     \
  RS_STAGE(8, 4)     \
  RS_STAGE(16, 2)    \
  RS_STAGE(32, 1)

// ---------- kernel 0: zero the accumulator region of the workspace ----------
__global__ __launch_bounds__(256) void zero_kernel(float4* __restrict__ p, int n4) {
  int i = blockIdx.x * blockDim.x + threadIdx.x;
  if (i < n4) p[i] = make_float4(0.f, 0.f, 0.f, 0.f);
}

// ---------- kernel 1: per-graph count + coord sums -> acc[B][4] ----------
__global__ __launch_bounds__(256) void pool_kernel(
    const float* __restrict__ coords, const int* __restrict__ batch,
    float* __restrict__ acc, int n) {
  int e = blockIdx.x * blockDim.x + threadIdx.x;
  int lane = threadIdx.x & 63;
  int ec = min(e, n - 1);
  bool valid = (e < n);
  int g = batch[ec];
  float s0 = valid ? 1.0f : 0.0f;
  float s1 = valid ? coords[ec * 3 + 0] : 0.0f;
  float s2 = valid ? coords[ec * 3 + 1] : 0.0f;
  float s3 = valid ? coords[ec * 3 + 2] : 0.0f;

  int gfirst = __builtin_amdgcn_readfirstlane(g);
  int glast  = __builtin_amdgcn_readfirstlane(__shfl(g, 63, 64));

  if (gfirst == glast) {
    float t0 = s0, t1 = s1, t2 = s2, t3 = s3;
#pragma unroll
    for (int m = 1; m < 64; m <<= 1) {
      t0 += __shfl_xor(t0, m, 64);
      t1 += __shfl_xor(t1, m, 64);
      t2 += __shfl_xor(t2, m, 64);
      t3 += __shfl_xor(t3, m, 64);
    }
    if (lane < 4) {
      float val = (lane == 0) ? t0 : (lane == 1) ? t1 : (lane == 2) ? t2 : t3;
      atomicAdd(&acc[gfirst * 4 + lane], val);
    }
  } else {
    for (int gc = gfirst; gc <= glast; ++gc) {
      bool in = (g == gc);
      float t0 = in ? s0 : 0.0f, t1 = in ? s1 : 0.0f;
      float t2 = in ? s2 : 0.0f, t3 = in ? s3 : 0.0f;
#pragma unroll
      for (int m = 1; m < 64; m <<= 1) {
        t0 += __shfl_xor(t0, m, 64);
        t1 += __shfl_xor(t1, m, 64);
        t2 += __shfl_xor(t2, m, 64);
        t3 += __shfl_xor(t3, m, 64);
      }
      if (lane < 4) {
        float val = (lane == 0) ? t0 : (lane == 1) ? t1 : (lane == 2) ? t2 : t3;
        atomicAdd(&acc[gc * 4 + lane], val);
      }
    }
  }
}

// ---------- kernel 2: per-edge basis + outer product, segment-sum -> V[B][64]
__global__ __launch_bounds__(256) void edge_kernel(
    const float* __restrict__ x, const float* __restrict__ coords,
    const int* __restrict__ batch, const float* __restrict__ acc,
    float* __restrict__ V, int n) {
  int e = blockIdx.x * blockDim.x + threadIdx.x;
  int lane = threadIdx.x & 63;
  int ec = min(e, n - 1);
  bool valid = (e < n);
  int g = batch[ec];

  float cx = coords[ec * 3 + 0];
  float cy = coords[ec * 3 + 1];
  float cz = coords[ec * 3 + 2];
  float4 a4 = ((const float4*)acc)[g];  // {cnt, sx, sy, sz}
  float inv = 1.0f / fmaxf(a4.x, 1.0f);
  float rx = a4.y * inv - cx;
  float ry = a4.z * inv - cy;
  float rz = a4.w * inv - cz;
  float d2 = rx * rx + ry * ry + rz * rz;
  float d = sqrtf(d2);
  // rings = {0, 4}, sigma = 4
  float r0 = __expf(-0.03125f * d2);          // exp(-0.5*(d/4)^2)
  float tt = (d - 4.0f) * 0.25f;
  float r1 = __expf(-0.5f * tt * tt);
  float idm = 1.0f / fmaxf(d, 1e-6f);
  float ax = rx * idm, ay = ry * idm, az = rz * idm;
  float bas[8] = {r0, r0 * ax, r0 * ay, r0 * az, r1, r1 * ax, r1 * ay, r1 * az};

  float4 xa = ((const float4*)x)[ec * 2];
  float4 xb = ((const float4*)x)[ec * 2 + 1];
  float xv[8] = {xa.x, xa.y, xa.z, xa.w, xb.x, xb.y, xb.z, xb.w};
  if (!valid) {
#pragma unroll
    for (int i = 0; i < 8; ++i) xv[i] = 0.0f;
  }

  int gfirst = __builtin_amdgcn_readfirstlane(g);
  int glast  = __builtin_amdgcn_readfirstlane(__shfl(g, 63, 64));
  int dst = rev6(lane);

  float v[64];
  if (gfirst == glast) {
#pragma unroll
    for (int i = 0; i < 8; ++i)
#pragma unroll
      for (int b = 0; b < 8; ++b) v[i * 8 + b] = xv[i] * bas[b];
    RS_ALL();
    atomicAdd(&V[(size_t)gfirst * 64 + dst], v[0]);
  } else {
    for (int gc = gfirst; gc <= glast; ++gc) {
      bool in = (g == gc);
#pragma unroll
      for (int i = 0; i < 8; ++i)
#pragma unroll
        for (int b = 0; b < 8; ++b) v[i * 8 + b] = in ? xv[i] * bas[b] : 0.0f;
      RS_ALL();
      atomicAdd(&V[(size_t)gc * 64 + dst], v[0]);
    }
  }
}

// ---------- kernel 3: out_raw[g,o] = sum_k V[g,k]*W[o,k]; channel stats ----
__global__ __launch_bounds__(256) void gemm_stats_kernel(
    const float* __restrict__ V, const float* __restrict__ W,
    float* __restrict__ out_raw, float* __restrict__ stats, int B) {
  __shared__ float Wl[32][65];   // +1 pad: (65*o+k)%32 = (o+k)%32, conflict-free
  __shared__ float Vl[8][64];
  __shared__ float ssum[32], ssq[32];
  int t = threadIdx.x;
  for (int idx = t; idx < 32 * 64; idx += 256) Wl[idx >> 6][idx & 63] = W[idx];
  int g0 = blockIdx.x * 8;
  for (int idx = t; idx < 8 * 64; idx += 256) Vl[idx >> 6][idx & 63] = V[(size_t)g0 * 64 + idx];
  if (t < 32) { ssum[t] = 0.0f; ssq[t] = 0.0f; }
  __syncthreads();

  int gl = t >> 5;
  int o = t & 31;
  float r = 0.0f;
#pragma unroll
  for (int k = 0; k < 64; ++k) r += Vl[gl][k] * Wl[o][k];
  out_raw[(size_t)(g0 + gl) * 32 + o] = r;
  atomicAdd(&ssum[o], r);
  atomicAdd(&ssq[o], r * r);
  __syncthreads();
  if (t < 32) {
    atomicAdd(&stats[t], ssum[t]);
    atomicAdd(&stats[32 + t], ssq[t]);
  }
}

// ---------- kernel 4: batchnorm + relu(|.|-bias) ----------
__global__ __launch_bounds__(256) void final_kernel(
    const float* __restrict__ out_raw, const float* __restrict__ stats,
    const float* __restrict__ gamma, const float* __restrict__ beta,
    const float* __restrict__ act_bias, float* __restrict__ out, int B) {
  int t = blockIdx.x * blockDim.x + threadIdx.x;
  if (t >= B * 32) return;
  int o = t & 31;
  float invB = 1.0f / (float)B;
  float mu = stats[o] * invB;
  float var = stats[32 + o] * invB - mu * mu;
  float xn = (out_raw[t] - mu) * rsqrtf(var + 1e-5f) * gamma[o] + beta[o];
  float y = fabsf(xn) - act_bias[o];
  out[t] = fmaxf(y, 0.0f);
}

extern "C" void kernel_launch(void* const* d_in, const int* in_sizes, int n_in,
                              void* d_out, int out_size, void* d_ws, size_t ws_size,
                              hipStream_t stream) {
  const float* x      = (const float*)d_in[0];
  const float* coords = (const float*)d_in[1];
  const int*   batch  = (const int*)d_in[2];
  const float* W      = (const float*)d_in[3];
  const float* gamma  = (const float*)d_in[4];
  const float* beta   = (const float*)d_in[5];
  const float* abias  = (const float*)d_in[6];
  float* out = (float*)d_out;

  int n = in_sizes[2];          // N points
  int B = out_size / 32;        // graphs

  // workspace layout (floats): acc[B*4] | V[B*64] | stats[64] | out_raw[B*32]
  float* acc     = (float*)d_ws;
  float* V       = acc + (size_t)B * 4;
  float* stats   = V + (size_t)B * 64;
  float* out_raw = stats + 64;
  int zero_floats = B * 4 + B * 64 + 64;           // acc + V + stats
  int n4 = zero_floats / 4;                        // all counts are %4==0
  zero_kernel<<<(n4 + 255) / 256, 256, 0, stream>>>((float4*)d_ws, n4);

  int blk = 256;
  int nblocks = (n + blk - 1) / blk;
  pool_kernel<<<nblocks, blk, 0, stream>>>(coords, batch, acc, n);
  edge_kernel<<<nblocks, blk, 0, stream>>>(x, coords, batch, acc, V, n);
  gemm_stats_kernel<<<B / 8, 256, 0, stream>>>(V, W, out_raw, stats, B);
  final_kernel<<<(B * 32 + 255) / 256, 256, 0, stream>>>(out_raw, stats, gamma, beta, abias, out, B);
}

// Round 4
// 32.161 us; speedup vs baseline: 1.6674x; 1.4794x over previous
//
#include <hip/hip_runtime.h>

// Problem constants (fixed by the reference): C_IN=8, C_OUT=32, N_RINGS=2,
// WIDTH=4.0, sigma=4.0, rings={0,4}. n and B derived at runtime.
// batch is SORTED -> each graph's points are a contiguous index range.

// One recursive-halving reduce-scatter stage with LITERAL constants so every
// v[] index is compile-time constant (keeps v[] in VGPRs — runtime indexing
// demotes the array to scratch: round-0 showed VGPR=68 / VALUBusy 0.25%).
#define RS_STAGE(M, HALF)                                   \
  {                                                         \
    const bool hi_ = (lane & (M)) != 0;                     \
    _Pragma("unroll")                                       \
    for (int k = 0; k < (HALF); ++k) {                      \
      float send = hi_ ? v[k] : v[(HALF) + k];              \
      float keep = hi_ ? v[(HALF) + k] : v[k];              \
      v[k] = keep + __shfl_xor(send, (M), 64);              \
    }                                                       \
  }

// After all 6 stages, v[0] = sum over the wave's lanes of original component
// rev6(lane), where rev6 is the 6-bit bit-reversal.
#define RS_ALL()     \
  RS_STAGE(1, 32)    \
  RS_STAGE(2, 16)    \
  RS_STAGE(4, 8)     \
  RS_STAGE(8, 4)     \
  RS_STAGE(16, 2)    \
  RS_STAGE(32, 1)

__device__ __forceinline__ int rev6(int l) {
  return ((l & 1) << 5) | ((l & 2) << 3) | ((l & 4) << 1) |
         ((l & 8) >> 1) | ((l & 16) >> 3) | ((l & 32) >> 5);
}

// ---------- kernel 1: graph boundaries from sorted batch + zero stats -------
// start[g] = first index i with batch[i] >= g; start[B] = n. Handles empty
// graphs (consecutive equal start values).
__global__ __launch_bounds__(256) void boundary_kernel(
    const int* __restrict__ batch, int* __restrict__ start,
    float* __restrict__ stats, int n, int B) {
  int i = blockIdx.x * blockDim.x + threadIdx.x;
  if (i < 64) stats[i] = 0.0f;
  if (i == 0) {
    int b0 = batch[0];
    for (int g = 0; g <= b0; ++g) start[g] = 0;
  }
  if (i < n - 1) {
    int a = batch[i], b = batch[i + 1];
    for (int g = a + 1; g <= b; ++g) start[g] = i + 1;
  } else if (i == n - 1) {
    int a = batch[n - 1];
    for (int g = a + 1; g <= B; ++g) start[g] = n;
  }
}

// ---------- kernel 2: one block per graph: mean -> basis -> V -> GEMM -------
__global__ __launch_bounds__(256) void graph_kernel(
    const float* __restrict__ x, const float* __restrict__ coords,
    const int* __restrict__ start, const float* __restrict__ W,
    float* __restrict__ out_raw) {
  __shared__ float sred[4][64];   // cross-wave reduction scratch
  __shared__ float sVg[64];       // per-graph aggregated V
  __shared__ float pre2[4][32];   // GEMM partials
  __shared__ float smean[3];

  const int g = blockIdx.x;
  const int lo = start[g], hi = start[g + 1];
  const int t = threadIdx.x;
  const int lane = t & 63;
  const int wv = t >> 6;

  // ---- pass 1: coord sums -> mean ----
  float s1 = 0.f, s2 = 0.f, s3 = 0.f;
  for (int i = lo + t; i < hi; i += 256) {
    s1 += coords[(size_t)i * 3 + 0];
    s2 += coords[(size_t)i * 3 + 1];
    s3 += coords[(size_t)i * 3 + 2];
  }
#pragma unroll
  for (int m = 1; m < 64; m <<= 1) {
    s1 += __shfl_xor(s1, m, 64);
    s2 += __shfl_xor(s2, m, 64);
    s3 += __shfl_xor(s3, m, 64);
  }
  if (lane == 0) { sred[wv][0] = s1; sred[wv][1] = s2; sred[wv][2] = s3; }
  __syncthreads();
  if (t == 0) {
    float inv = 1.0f / (float)max(hi - lo, 1);
    smean[0] = (sred[0][0] + sred[1][0] + sred[2][0] + sred[3][0]) * inv;
    smean[1] = (sred[0][1] + sred[1][1] + sred[2][1] + sred[3][1]) * inv;
    smean[2] = (sred[0][2] + sred[1][2] + sred[2][2] + sred[3][2]) * inv;
  }
  __syncthreads();
  const float mx = smean[0], my = smean[1], mz = smean[2];

  // ---- pass 2: per-point basis x feature outer product, accumulate v[64] ----
  float v[64];
#pragma unroll
  for (int k = 0; k < 64; ++k) v[k] = 0.f;

  for (int i = lo + t; i < hi; i += 256) {
    float cx = coords[(size_t)i * 3 + 0];
    float cy = coords[(size_t)i * 3 + 1];
    float cz = coords[(size_t)i * 3 + 2];
    float rx = mx - cx, ry = my - cy, rz = mz - cz;
    float d2 = rx * rx + ry * ry + rz * rz;
    float d = sqrtf(d2);
    // rings = {0, 4}, sigma = 4
    float r0 = __expf(-0.03125f * d2);        // exp(-0.5*(d/4)^2)
    float tt = (d - 4.0f) * 0.25f;
    float r1 = __expf(-0.5f * tt * tt);
    float idm = 1.0f / fmaxf(d, 1e-6f);
    float ax = rx * idm, ay = ry * idm, az = rz * idm;
    float bas[8] = {r0, r0 * ax, r0 * ay, r0 * az,
                    r1, r1 * ax, r1 * ay, r1 * az};
    float4 xa = ((const float4*)x)[2 * (size_t)i];
    float4 xb = ((const float4*)x)[2 * (size_t)i + 1];
    float xv[8] = {xa.x, xa.y, xa.z, xa.w, xb.x, xb.y, xb.z, xb.w};
#pragma unroll
    for (int i8 = 0; i8 < 8; ++i8)
#pragma unroll
      for (int b = 0; b < 8; ++b) v[i8 * 8 + b] += xv[i8] * bas[b];
  }

  // wave reduce-scatter, then cross-wave combine in LDS
  RS_ALL();
  sred[wv][rev6(lane)] = v[0];
  __syncthreads();
  if (t < 64) sVg[t] = sred[0][t] + sred[1][t] + sred[2][t] + sred[3][t];
  __syncthreads();

  // ---- per-graph GEMM: out[o] = sum_k Vg[k] * W[o*64+k] ----
  const int o = t & 31;
  const int part = t >> 5;              // 0..7, 8 k-chunks of 8
  const float* wrow = W + (size_t)o * 64 + part * 8;
  float4 w0 = *(const float4*)(wrow);
  float4 w1 = *(const float4*)(wrow + 4);
  float4 v0 = *(const float4*)(&sVg[part * 8]);
  float4 v1 = *(const float4*)(&sVg[part * 8 + 4]);
  float r = w0.x * v0.x + w0.y * v0.y + w0.z * v0.z + w0.w * v0.w +
            w1.x * v1.x + w1.y * v1.y + w1.z * v1.z + w1.w * v1.w;
  r += __shfl_xor(r, 32, 64);           // combine part pairs within wave
  if (lane < 32) pre2[wv][o] = r;
  __syncthreads();
  if (t < 32)
    out_raw[(size_t)g * 32 + t] =
        pre2[0][t] + pre2[1][t] + pre2[2][t] + pre2[3][t];
}

// ---------- kernel 3: per-channel sum / sumsq over out_raw ----------
__global__ __launch_bounds__(256) void stats_kernel(
    const float* __restrict__ out_raw, float* __restrict__ stats, int B) {
  __shared__ float red[4][32], redq[4][32];
  const int t = threadIdx.x;
  const int o = t & 31;
  const int lane = t & 63;
  const int wv = t >> 6;
  const int stride = gridDim.x * 256;   // multiple of 32 -> o constant/thread
  float s = 0.f, q = 0.f;
  for (int e = blockIdx.x * 256 + t; e < B * 32; e += stride) {
    float val = out_raw[e];
    s += val;
    q += val * val;
  }
  s += __shfl_xor(s, 32, 64);
  q += __shfl_xor(q, 32, 64);
  if (lane < 32) { red[wv][o] = s; redq[wv][o] = q; }
  __syncthreads();
  if (t < 32) {
    atomicAdd(&stats[t],      red[0][t] + red[1][t] + red[2][t] + red[3][t]);
    atomicAdd(&stats[32 + t], redq[0][t] + redq[1][t] + redq[2][t] + redq[3][t]);
  }
}

// ---------- kernel 4: batchnorm + relu(|.|-bias) ----------
__global__ __launch_bounds__(256) void final_kernel(
    const float* __restrict__ out_raw, const float* __restrict__ stats,
    const float* __restrict__ gamma, const float* __restrict__ beta,
    const float* __restrict__ act_bias, float* __restrict__ out, int B) {
  int t = blockIdx.x * blockDim.x + threadIdx.x;
  if (t >= B * 32) return;
  int o = t & 31;
  float invB = 1.0f / (float)B;
  float mu = stats[o] * invB;
  float var = stats[32 + o] * invB - mu * mu;
  float xn = (out_raw[t] - mu) * rsqrtf(var + 1e-5f) * gamma[o] + beta[o];
  float y = fabsf(xn) - act_bias[o];
  out[t] = fmaxf(y, 0.0f);
}

extern "C" void kernel_launch(void* const* d_in, const int* in_sizes, int n_in,
                              void* d_out, int out_size, void* d_ws, size_t ws_size,
                              hipStream_t stream) {
  const float* x      = (const float*)d_in[0];
  const float* coords = (const float*)d_in[1];
  const int*   batch  = (const int*)d_in[2];
  const float* W      = (const float*)d_in[3];
  const float* gamma  = (const float*)d_in[4];
  const float* beta   = (const float*)d_in[5];
  const float* abias  = (const float*)d_in[6];
  float* out = (float*)d_out;

  int n = in_sizes[2];          // N points
  int B = out_size / 32;        // graphs

  // ws layout: start[B+1] ints | pad | stats[64] floats | out_raw[B*32] floats
  int*   start   = (int*)d_ws;
  int    stats_off = ((B + 1 + 3) / 4) * 4;          // 16B-align
  float* stats   = (float*)d_ws + stats_off;
  float* out_raw = stats + 64;

  boundary_kernel<<<(n + 255) / 256, 256, 0, stream>>>(batch, start, stats, n, B);
  graph_kernel<<<B, 256, 0, stream>>>(x, coords, start, W, out_raw);
  stats_kernel<<<64, 256, 0, stream>>>(out_raw, stats, B);
  final_kernel<<<(B * 32 + 255) / 256, 256, 0, stream>>>(out_raw, stats, gamma, beta, abias, out, B);
}